// Round 1
// baseline (400.286 us; speedup 1.0000x reference)
//
#include <hip/hip_runtime.h>
#include <math.h>

#define Tn 64
#define Bn 128
#define MUc 0.1f
#define REGc 1e-6f

// One block per batch element. 576 = 24*24 threads (one per Qh element).
// Backward scan (t = 63..0) then forward rollout, all in one kernel.
__global__ __launch_bounds__(576) void ipddp_kernel(
    const float* __restrict__ Qg, const float* __restrict__ qg,
    const float* __restrict__ Fg, const float* __restrict__ Gg,
    const float* __restrict__ Wg, const float* __restrict__ cg,
    const float* __restrict__ sg, const float* __restrict__ VTg,
    const float* __restrict__ vTg, const float* __restrict__ x0g,
    const float* __restrict__ xnomg, const float* __restrict__ unomg,
    float* __restrict__ outg)
{
  const int b   = blockIdx.x;
  const int tid = threadIdx.x;
  const int qi  = tid / 24;          // Qh row
  const int qj  = tid - qi * 24;     // Qh col

  __shared__ float Vls[256];                    // V carry [n][m]
  __shared__ float vls[16];                     // v carry
  __shared__ float Vtt[256];                    // Vn before symmetrize
  __shared__ float Fs[384];                     // F [n][d]
  __shared__ alignas(16) float FsT[384];        // F^T [d][n]
  __shared__ alignas(16) float WT[192];         // W^T [d][c]
  __shared__ alignas(16) float WTs[192];        // W^T * sc [d][c]
  __shared__ float qst[24];
  __shared__ float scls[8];
  __shared__ float w2ls[8];
  __shared__ float qhls[24];
  __shared__ alignas(16) float FtVls[384];      // (F^T V) [i][m]
  __shared__ float Qhls[576];
  __shared__ float Zls[128];                    // Qux + Quu*Kt  [m][n]
  __shared__ float zls[8];                      // qu + Quu*kt
  __shared__ float KkAll[64 * 136];             // per t: Kt[m][n] at m*17+n, kt at m*17+16
  __shared__ float FsR[8 * 384];                // forward-pass F ring
  __shared__ float dxb[2][16];

  float gcur[16];
  float rQ;

  // ---------------- prologue: stage t = T-1, init V,v ----------------
  {
    const size_t pb = (size_t)((Tn - 1) * Bn + b);
    rQ = Qg[pb * 576 + tid];
#pragma unroll
    for (int n = 0; n < 16; ++n) gcur[n] = Gg[pb * 9216 + (size_t)n * 576 + tid];
    float rF = 0.f, rW = 0.f, rq = 0.f, rc = 1.f, rs = 0.f;
    if (tid < 384) rF = Fg[pb * 384 + tid];
    else           rW = Wg[pb * 192 + (tid - 384)];
    if (tid < 24)  rq = qg[pb * 24 + tid];
    if (tid < 8) { rc = cg[pb * 8 + tid]; rs = sg[pb * 8 + tid]; }

    if (tid < 256) Vls[tid] = VTg[(size_t)b * 256 + tid];
    if (tid < 16)  vls[tid] = vTg[(size_t)b * 16 + tid];
    if (tid < 384) { Fs[tid] = rF; FsT[qj * 16 + qi] = rF; }
    else { const int idx = tid - 384; const int c = idx / 24, d = idx - c * 24; WT[d * 8 + c] = rW; }
    if (tid < 24) qst[tid] = rq;
    if (tid < 8) { const float rr = fmaf(rs, rc, MUc); scls[tid] = rs / rc; w2ls[tid] = rs - rr / rc; }
  }
  __syncthreads();

  // ---------------- backward scan ----------------
  for (int t = Tn - 1; t >= 0; --t) {
    // issue prefetch for t-1 (clamped; redundant at t==0, harmless)
    const int tp = (t > 0) ? (t - 1) : 0;
    const size_t pb = (size_t)(tp * Bn + b);
    const float nQ = Qg[pb * 576 + tid];
    float gn[16];
#pragma unroll
    for (int n = 0; n < 16; ++n) gn[n] = Gg[pb * 9216 + (size_t)n * 576 + tid];
    float nF = 0.f, nW = 0.f, nq = 0.f, nc = 1.f, ns = 0.f;
    if (tid < 384) nF = Fg[pb * 384 + tid];
    else           nW = Wg[pb * 192 + (tid - 384)];
    if (tid < 24)  nq = qg[pb * 24 + tid];
    if (tid < 8) { nc = cg[pb * 8 + tid]; ns = sg[pb * 8 + tid]; }

    // P1: FtV = F^T V ; WTs = W^T*sc ; qh
    if (tid < 384) {
      const int ii = tid >> 4, mm = tid & 15;
      float a = 0.f;
#pragma unroll
      for (int n = 0; n < 16; ++n) a = fmaf(Fs[n * 24 + ii], Vls[n * 16 + mm], a);
      FtVls[tid] = a;
    } else {
      const int idx = tid - 384;
      WTs[idx] = WT[idx] * scls[idx & 7];
    }
    if (tid < 24) {
      float a = qst[tid];
#pragma unroll
      for (int n = 0; n < 16; ++n) a = fmaf(Fs[n * 24 + tid], vls[n], a);
#pragma unroll
      for (int c = 0; c < 8; ++c) a = fmaf(WT[tid * 8 + c], w2ls[c], a);
      qhls[tid] = a;
    }
    __syncthreads();

    // P2: Qh[i][j]
    {
      float acc = rQ;
      const float4* fa = (const float4*)(FtVls + qi * 16);
      const float4* fb = (const float4*)(FsT + qj * 16);
#pragma unroll
      for (int r = 0; r < 4; ++r) {
        const float4 x4 = fa[r], y4 = fb[r];
        acc = fmaf(x4.x, y4.x, acc); acc = fmaf(x4.y, y4.y, acc);
        acc = fmaf(x4.z, y4.z, acc); acc = fmaf(x4.w, y4.w, acc);
      }
#pragma unroll
      for (int n = 0; n < 16; ++n) acc = fmaf(vls[n], gcur[n], acc);
      const float4* wa = (const float4*)(WT + qi * 8);
      const float4* wb = (const float4*)(WTs + qj * 8);
#pragma unroll
      for (int r = 0; r < 2; ++r) {
        const float4 x4 = wa[r], y4 = wb[r];
        acc = fmaf(x4.x, -y4.x, acc); acc = fmaf(x4.y, -y4.y, acc);
        acc = fmaf(x4.z, -y4.z, acc); acc = fmaf(x4.w, -y4.w, acc);
      }
      Qhls[tid] = acc;
    }
    __syncthreads();

    // P3: wave 0 — 8x8 LU (partial pivot) with 17 RHS, column-per-lane; then Z,z
    if (tid < 64) {
      const int l = tid;
      float colv[8];
#pragma unroll
      for (int a = 0; a < 8; ++a) colv[a] = 0.f;
      if (l < 8) {
#pragma unroll
        for (int a = 0; a < 8; ++a) colv[a] = Qhls[(16 + a) * 24 + 16 + l];
        colv[l] += REGc;
      } else if (l < 24) {
#pragma unroll
        for (int a = 0; a < 8; ++a) colv[a] = Qhls[(16 + a) * 24 + (l - 8)];
      } else if (l == 24) {
#pragma unroll
        for (int a = 0; a < 8; ++a) colv[a] = qhls[16 + a];
      }
#pragma unroll
      for (int k = 0; k < 8; ++k) {
        float ck[8];
#pragma unroll
        for (int a = 0; a < 8; ++a) ck[a] = __shfl(colv[a], k);
        int p = k; float best = fabsf(ck[k]);
#pragma unroll
        for (int a = k + 1; a < 8; ++a) { const float w = fabsf(ck[a]); if (w > best) { best = w; p = a; } }
#pragma unroll
        for (int a = k + 1; a < 8; ++a) {
          if (p == a) {
            float t0 = ck[k]; ck[k] = ck[a]; ck[a] = t0;
            t0 = colv[k]; colv[k] = colv[a]; colv[a] = t0;
          }
        }
        const float inv = 1.0f / ck[k];
#pragma unroll
        for (int a = k + 1; a < 8; ++a) {
          const float m = ck[a] * inv;
          colv[a] = fmaf(-m, colv[k], colv[a]);
        }
      }
      float x[8];
#pragma unroll
      for (int a = 7; a >= 0; --a) {
        float acc = colv[a];
#pragma unroll
        for (int j2 = a + 1; j2 < 8; ++j2) acc = fmaf(-__shfl(colv[a], j2), x[j2], acc);
        x[a] = acc / __shfl(colv[a], a);
      }
      if (l >= 8 && l <= 24) {
        float* kk = &KkAll[t * 136];
        const int cc = l - 8;
#pragma unroll
        for (int a = 0; a < 8; ++a) kk[a * 17 + cc] = -x[a];
      }
      if (l >= 8 && l < 24) {
        const int jj = l - 8;
#pragma unroll
        for (int a = 0; a < 8; ++a) {
          float zz = Qhls[(16 + a) * 24 + jj];
#pragma unroll
          for (int mb = 0; mb < 8; ++mb) zz = fmaf(Qhls[(16 + a) * 24 + 16 + mb], -x[mb], zz);
          Zls[a * 16 + jj] = zz;
        }
      } else if (l == 24) {
#pragma unroll
        for (int a = 0; a < 8; ++a) {
          float zz = qhls[16 + a];
#pragma unroll
          for (int mb = 0; mb < 8; ++mb) zz = fmaf(Qhls[(16 + a) * 24 + 16 + mb], -x[mb], zz);
          zls[a] = zz;
        }
      }
    }
    __syncthreads();

    // P4: Vn (pre-sym) and v_new
    if (tid < 256) {
      const int ii = tid >> 4, jj = tid & 15;
      const float* kk = &KkAll[t * 136];
      float acc = Qhls[ii * 24 + jj];
#pragma unroll
      for (int m = 0; m < 8; ++m) acc = fmaf(Qhls[ii * 24 + 16 + m], kk[m * 17 + jj], acc);
#pragma unroll
      for (int m = 0; m < 8; ++m) acc = fmaf(kk[m * 17 + ii], Zls[m * 16 + jj], acc);
      Vtt[tid] = acc;
    } else if (tid < 272) {
      const int ii = tid - 256;
      const float* kk = &KkAll[t * 136];
      float acc = qhls[ii];
#pragma unroll
      for (int m = 0; m < 8; ++m) acc = fmaf(Qhls[ii * 24 + 16 + m], kk[m * 17 + 16], acc);
#pragma unroll
      for (int m = 0; m < 8; ++m) acc = fmaf(kk[m * 17 + ii], zls[m], acc);
      vls[ii] = acc;
    }
    __syncthreads();

    // P5: symmetrize V carry; stage t-1 into LDS; rotate registers
    if (tid < 256) Vls[tid] = 0.5f * (Vtt[tid] + Vtt[((tid & 15) << 4) | (tid >> 4)]);
    if (tid < 384) { Fs[tid] = nF; FsT[qj * 16 + qi] = nF; }
    else { const int idx = tid - 384; const int c = idx / 24, d = idx - c * 24; WT[d * 8 + c] = nW; }
    if (tid < 24) qst[tid] = nq;
    if (tid < 8) { const float rr = fmaf(ns, nc, MUc); scls[tid] = ns / nc; w2ls[tid] = ns - rr / nc; }
    rQ = nQ;
#pragma unroll
    for (int n = 0; n < 16; ++n) gcur[n] = gn[n];
    __syncthreads();
  }

  // ---------------- forward rollout ----------------
  float rfA = 0.f, rfB = 0.f, rfC = 0.f;
  if (tid >= 192) {
    const int sidx = tid - 192;
#pragma unroll
    for (int tt = 0; tt < 4; ++tt)
      FsR[tt * 384 + sidx] = Fg[(size_t)(tt * Bn + b) * 384 + sidx];
    rfA = Fg[(size_t)(4 * Bn + b) * 384 + sidx];
    rfB = Fg[(size_t)(5 * Bn + b) * 384 + sidx];
    rfC = Fg[(size_t)(6 * Bn + b) * 384 + sidx];
  }
  if (tid < 16) dxb[0][tid] = x0g[(size_t)b * 16 + tid] - xnomg[(size_t)b * 16 + tid];
  __syncthreads();

  for (int t = 0; t < Tn; ++t) {
    if (tid < 16) {
      const float* cur = dxb[t & 1];
      float* nxt = dxb[(t + 1) & 1];
      const float* kk = &KkAll[t * 136];
      float du[8];
#pragma unroll
      for (int m2 = 0; m2 < 8; ++m2) {
        float a = kk[m2 * 17 + 16];
#pragma unroll
        for (int n = 0; n < 16; ++n) a = fmaf(kk[m2 * 17 + n], cur[n], a);
        du[m2] = a;
        if (tid == m2) {
          const size_t o = (size_t)(t * Bn + b) * 8 + m2;
          outg[o] = unomg[o] + a;
        }
      }
      const float* fr = &FsR[(t & 7) * 384 + tid * 24];
      float a = 0.f;
#pragma unroll
      for (int k2 = 0; k2 < 16; ++k2) a = fmaf(fr[k2], cur[k2], a);
#pragma unroll
      for (int m2 = 0; m2 < 8; ++m2) a = fmaf(fr[16 + m2], du[m2], a);
      nxt[tid] = a;
    }
    if (tid >= 192) {
      const int sidx = tid - 192;
      if (t + 4 < Tn) FsR[((t + 4) & 7) * 384 + sidx] = rfA;
      rfA = rfB; rfB = rfC;
      if (t + 7 < Tn) rfC = Fg[(size_t)((t + 7) * Bn + b) * 384 + sidx];
    }
    __syncthreads();
  }
}

extern "C" void kernel_launch(void* const* d_in, const int* in_sizes, int n_in,
                              void* d_out, int out_size, void* d_ws, size_t ws_size,
                              hipStream_t stream) {
  (void)in_sizes; (void)n_in; (void)out_size; (void)d_ws; (void)ws_size;
  const float* Qg    = (const float*)d_in[0];
  const float* qg    = (const float*)d_in[1];
  const float* Fg    = (const float*)d_in[2];
  const float* Gg    = (const float*)d_in[3];
  const float* Wg    = (const float*)d_in[4];
  const float* cg    = (const float*)d_in[5];
  const float* sg    = (const float*)d_in[6];
  const float* VTg   = (const float*)d_in[7];
  const float* vTg   = (const float*)d_in[8];
  const float* x0g   = (const float*)d_in[9];
  const float* xnomg = (const float*)d_in[10];
  const float* unomg = (const float*)d_in[11];
  float* outg = (float*)d_out;

  ipddp_kernel<<<dim3(Bn), dim3(576), 0, stream>>>(
      Qg, qg, Fg, Gg, Wg, cg, sg, VTg, vTg, x0g, xnomg, unomg, outg);
}

// Round 2
// 290.012 us; speedup vs baseline: 1.3802x; 1.3802x over previous
//
#include <hip/hip_runtime.h>
#include <math.h>

#define Tn 64
#define Bn 128
#define MUc 0.1f
#define REGc 1e-6f

// One block per batch element (128 blocks). Backward Riccati scan (t=63..0)
// with 4 barriers/step + wave-specialized LU phase, then pipelined forward
// rollout. Critical-path-optimized: no-pivot LU (Quu is strongly PD),
// staging overlapped with LU, symmetrize fused into Vn.
__global__ __launch_bounds__(576, 1) void ipddp_kernel(
    const float* __restrict__ Qg, const float* __restrict__ qg,
    const float* __restrict__ Fg, const float* __restrict__ Gg,
    const float* __restrict__ Wg, const float* __restrict__ cg,
    const float* __restrict__ sg, const float* __restrict__ VTg,
    const float* __restrict__ vTg, const float* __restrict__ x0g,
    const float* __restrict__ xnomg, const float* __restrict__ unomg,
    float* __restrict__ outg)
{
  const int b   = blockIdx.x;
  const int tid = threadIdx.x;
  const int qi  = tid / 24;          // Qh row
  const int qj  = tid - qi * 24;     // Qh col

  __shared__ float Vls[256];                    // V carry [n][m]
  __shared__ float vls[16];                     // v carry
  __shared__ float Fs[384];                     // F [n=16][d=24]
  __shared__ alignas(16) float FsT[480];        // F^T [d=24][pad 20]
  __shared__ alignas(16) float WT[288];         // W^T [d=24][pad 12]
  __shared__ alignas(16) float WTs[288];        // W^T * sc, padded
  __shared__ float qst[24];
  __shared__ float qhls[24];
  __shared__ float scls[8];
  __shared__ float w2ls[8];
  __shared__ alignas(16) float FtVls[384];      // (F^T V) [i=24][m=16]
  __shared__ float Qhls[576];
  __shared__ float Zls[128];                    // Qux + Quu*Kt  [m][n]
  __shared__ float zls[8];                      // qu + Quu*kt
  __shared__ float KkAll[64 * 136];             // per t: Kt at m*17+n, kt at m*17+16
  __shared__ alignas(16) float Ms[2][272];      // fwd M, stride 17
  __shared__ float bs[2][16];
  __shared__ float dxAll[65 * 16];
  __shared__ float FsRing[4 * 384];

  float gcur[16];
  float rQ;

  // ---------------- prologue: stage t = T-1, init V,v ----------------
  {
    const size_t pb = (size_t)((Tn - 1) * Bn + b);
    rQ = Qg[pb * 576 + tid];
#pragma unroll
    for (int n = 0; n < 16; ++n) gcur[n] = Gg[pb * 9216 + (size_t)n * 576 + tid];
    if (tid >= 64 && tid < 448) {
      const int s = tid - 64; const float v = Fg[pb * 384 + s];
      const int n = s / 24, d = s - n * 24;
      Fs[s] = v; FsT[d * 20 + n] = v;
    } else if (tid >= 448 && tid < 544) {
      const int j = tid - 448;
      const float w0 = Wg[pb * 192 + 2 * j], w1 = Wg[pb * 192 + 2 * j + 1];
      const int i0 = 2 * j, i1 = 2 * j + 1;
      WT[(i0 % 24) * 12 + i0 / 24] = w0;
      WT[(i1 % 24) * 12 + i1 / 24] = w1;
    } else if (tid >= 544 && tid < 568) {
      qst[tid - 544] = qg[pb * 24 + (tid - 544)];
    } else if (tid >= 568) {
      const int c = tid - 568;
      const float cc = cg[pb * 8 + c], ss = sg[pb * 8 + c];
      const float rr = fmaf(ss, cc, MUc);
      scls[c] = ss / cc; w2ls[c] = ss - rr / cc;
    }
    if (tid < 256) Vls[tid] = VTg[(size_t)b * 256 + tid];
    if (tid < 16)  vls[tid] = vTg[(size_t)b * 16 + tid];
  }
  __syncthreads();

  // ---------------- backward scan ----------------
  for (int t = Tn - 1; t >= 0; --t) {
    // prefetch t-1 (clamped at t==0; redundant, harmless)
    const int tp = (t > 0) ? (t - 1) : 0;
    const size_t pb = (size_t)(tp * Bn + b);
    const float nQ = Qg[pb * 576 + tid];
    float gn[16];
#pragma unroll
    for (int n = 0; n < 16; ++n) gn[n] = Gg[pb * 9216 + (size_t)n * 576 + tid];
    float nF = 0.f, nW0 = 0.f, nW1 = 0.f, nq = 0.f, ncc = 1.f, nss = 0.f;
    if (tid >= 64 && tid < 448)       nF = Fg[pb * 384 + (tid - 64)];
    else if (tid >= 448 && tid < 544) { nW0 = Wg[pb * 192 + 2 * (tid - 448)];
                                        nW1 = Wg[pb * 192 + 2 * (tid - 448) + 1]; }
    else if (tid >= 544 && tid < 568) nq = qg[pb * 24 + (tid - 544)];
    else if (tid >= 568)              { ncc = cg[pb * 8 + (tid - 568)];
                                        nss = sg[pb * 8 + (tid - 568)]; }

    // Phase A: FtV = F^T V ; WTs = W^T*sc ; qh
    if (tid < 384) {
      const int ii = tid >> 4, mm = tid & 15;
      float a = 0.f;
#pragma unroll
      for (int n = 0; n < 16; ++n) a = fmaf(Fs[n * 24 + ii], Vls[n * 16 + mm], a);
      FtVls[tid] = a;
    } else {
      const int idx = tid - 384; const int d = idx >> 3, c = idx & 7;
      WTs[d * 12 + c] = WT[d * 12 + c] * scls[c];
    }
    if (tid < 24) {
      float a = qst[tid];
#pragma unroll
      for (int n = 0; n < 16; ++n) a = fmaf(Fs[n * 24 + tid], vls[n], a);
#pragma unroll
      for (int c = 0; c < 8; ++c) a = fmaf(WT[tid * 12 + c], w2ls[c], a);
      qhls[tid] = a;
    }
    __syncthreads();

    // Phase B: Qh[i][j]
    {
      float acc = rQ;
      const float4* fa = (const float4*)(FtVls + qi * 16);
      const float4* fb = (const float4*)(FsT + qj * 20);
#pragma unroll
      for (int r = 0; r < 4; ++r) {
        const float4 x4 = fa[r], y4 = fb[r];
        acc = fmaf(x4.x, y4.x, acc); acc = fmaf(x4.y, y4.y, acc);
        acc = fmaf(x4.z, y4.z, acc); acc = fmaf(x4.w, y4.w, acc);
      }
#pragma unroll
      for (int n = 0; n < 16; ++n) acc = fmaf(vls[n], gcur[n], acc);
      const float4* wa = (const float4*)(WT + qi * 12);
      const float4* wb = (const float4*)(WTs + qj * 12);
#pragma unroll
      for (int r = 0; r < 2; ++r) {
        const float4 x4 = wa[r], y4 = wb[r];
        acc = fmaf(x4.x, -y4.x, acc); acc = fmaf(x4.y, -y4.y, acc);
        acc = fmaf(x4.z, -y4.z, acc); acc = fmaf(x4.w, -y4.w, acc);
      }
      Qhls[tid] = acc;
    }
    __syncthreads();

    // Phase C: wave 0 — no-pivot LU (Quu strongly PD), 25 columns-per-lane;
    //          waves 1-8 — stage next-step LDS (F/W/q/c/s).
    if (tid < 64) {
      const int l = tid;
      float colv[8], invk[8];
#pragma unroll
      for (int a = 0; a < 8; ++a) colv[a] = 0.f;
      if (l < 8) {
#pragma unroll
        for (int a = 0; a < 8; ++a) colv[a] = Qhls[(16 + a) * 24 + 16 + l];
        colv[l] += REGc;
      } else if (l < 24) {
#pragma unroll
        for (int a = 0; a < 8; ++a) colv[a] = Qhls[(16 + a) * 24 + (l - 8)];
      } else if (l == 24) {
#pragma unroll
        for (int a = 0; a < 8; ++a) colv[a] = qhls[16 + a];
      }
#pragma unroll
      for (int k = 0; k < 8; ++k) {
        const float ckk = __shfl(colv[k], k);
        const float inv = 1.0f / ckk;
        invk[k] = inv;
#pragma unroll
        for (int a = k + 1; a < 8; ++a) {
          const float m = __shfl(colv[a], k) * inv;
          colv[a] = fmaf(-m, colv[k], colv[a]);
        }
      }
      float x[8];
#pragma unroll
      for (int a = 7; a >= 0; --a) {
        float acc = colv[a];
#pragma unroll
        for (int j2 = a + 1; j2 < 8; ++j2) acc = fmaf(-__shfl(colv[a], j2), x[j2], acc);
        x[a] = acc * invk[a];
      }
      if (l >= 8 && l <= 24) {
        float* kk = &KkAll[t * 136];
        const int cc = l - 8;
#pragma unroll
        for (int a = 0; a < 8; ++a) kk[a * 17 + cc] = -x[a];
      }
      if (l >= 8 && l < 24) {
        const int jj = l - 8;
#pragma unroll
        for (int a = 0; a < 8; ++a) {
          float zz = Qhls[(16 + a) * 24 + jj];
#pragma unroll
          for (int mb = 0; mb < 8; ++mb) zz = fmaf(Qhls[(16 + a) * 24 + 16 + mb], -x[mb], zz);
          Zls[a * 16 + jj] = zz;
        }
      } else if (l == 24) {
#pragma unroll
        for (int a = 0; a < 8; ++a) {
          float zz = qhls[16 + a];
#pragma unroll
          for (int mb = 0; mb < 8; ++mb) zz = fmaf(Qhls[(16 + a) * 24 + 16 + mb], -x[mb], zz);
          zls[a] = zz;
        }
      }
    } else {
      if (tid < 448) {
        const int s = tid - 64; const int n = s / 24, d = s - n * 24;
        Fs[s] = nF; FsT[d * 20 + n] = nF;
      } else if (tid < 544) {
        const int j = tid - 448; const int i0 = 2 * j, i1 = i0 + 1;
        WT[(i0 % 24) * 12 + i0 / 24] = nW0;
        WT[(i1 % 24) * 12 + i1 / 24] = nW1;
      } else if (tid < 568) {
        qst[tid - 544] = nq;
      } else {
        const int c = tid - 568;
        const float rr = fmaf(nss, ncc, MUc);
        scls[c] = nss / ncc; w2ls[c] = nss - rr / ncc;
      }
    }
    __syncthreads();

    // Phase D: Vn (symmetrized in one pass) and v_new; rotate prefetch regs
    {
      const float* kk = &KkAll[t * 136];
      if (tid < 256) {
        const int ii = tid >> 4, jj = tid & 15;
        float aij = Qhls[ii * 24 + jj];
        float aji = Qhls[jj * 24 + ii];
#pragma unroll
        for (int m = 0; m < 8; ++m) {
          aij = fmaf(Qhls[ii * 24 + 16 + m], kk[m * 17 + jj], aij);
          aji = fmaf(Qhls[jj * 24 + 16 + m], kk[m * 17 + ii], aji);
        }
#pragma unroll
        for (int m = 0; m < 8; ++m) {
          aij = fmaf(kk[m * 17 + ii], Zls[m * 16 + jj], aij);
          aji = fmaf(kk[m * 17 + jj], Zls[m * 16 + ii], aji);
        }
        Vls[tid] = 0.5f * (aij + aji);
      } else if (tid < 272) {
        const int ii = tid - 256;
        float acc = qhls[ii];
#pragma unroll
        for (int m = 0; m < 8; ++m) acc = fmaf(Qhls[ii * 24 + 16 + m], kk[m * 17 + 16], acc);
#pragma unroll
        for (int m = 0; m < 8; ++m) acc = fmaf(kk[m * 17 + ii], zls[m], acc);
        vls[ii] = acc;
      }
    }
    rQ = nQ;
#pragma unroll
    for (int n = 0; n < 16; ++n) gcur[n] = gn[n];
    __syncthreads();
  }

  // ---------------- forward rollout ----------------
  // ring slots 0..2 + register pipeline for F[t+3], F[t+4]
  float rfA0 = 0.f, rfA1 = 0.f, rfB0 = 0.f, rfB1 = 0.f;
  if (tid >= 384) {
    const int j = tid - 384;   // handles floats 2j, 2j+1
#pragma unroll
    for (int slot = 0; slot < 3; ++slot) {
      FsRing[slot * 384 + 2 * j]     = Fg[(size_t)(slot * Bn + b) * 384 + 2 * j];
      FsRing[slot * 384 + 2 * j + 1] = Fg[(size_t)(slot * Bn + b) * 384 + 2 * j + 1];
    }
    rfA0 = Fg[(size_t)(3 * Bn + b) * 384 + 2 * j];
    rfA1 = Fg[(size_t)(3 * Bn + b) * 384 + 2 * j + 1];
    rfB0 = Fg[(size_t)(4 * Bn + b) * 384 + 2 * j];
    rfB1 = Fg[(size_t)(4 * Bn + b) * 384 + 2 * j + 1];
  }
  if (tid < 16) dxAll[tid] = x0g[(size_t)b * 16 + tid] - xnomg[(size_t)b * 16 + tid];
  __syncthreads();

  // M0 = fx0 + fu0*K0, b0 = fu0*k0
  if (tid >= 64 && tid < 320) {
    const int idx = tid - 64; const int i = idx >> 4, j = idx & 15;
    const float* fr = &FsRing[i * 24];
    float a = fr[j];
#pragma unroll
    for (int m = 0; m < 8; ++m) a = fmaf(fr[16 + m], KkAll[m * 17 + j], a);
    Ms[0][i * 17 + j] = a;
  } else if (tid >= 320 && tid < 336) {
    const int i = tid - 320;
    const float* fr = &FsRing[i * 24];
    float a = 0.f;
#pragma unroll
    for (int m = 0; m < 8; ++m) a = fmaf(fr[16 + m], KkAll[m * 17 + 16], a);
    bs[0][i] = a;
  }
  __syncthreads();

  for (int t = 0; t < Tn; ++t) {
    const int cur = t & 1, nx = (t + 1) & 1;
    if (tid < 16) {
      const int i = tid;
      float a = bs[cur][i];
#pragma unroll
      for (int k2 = 0; k2 < 16; ++k2) a = fmaf(Ms[cur][i * 17 + k2], dxAll[t * 16 + k2], a);
      dxAll[(t + 1) * 16 + i] = a;
    } else if (tid >= 64 && tid < 320) {
      if (t + 1 < Tn) {
        const int idx = tid - 64; const int i = idx >> 4, j = idx & 15;
        const float* fr = &FsRing[((t + 1) & 3) * 384 + i * 24];
        const float* kn = &KkAll[(t + 1) * 136];
        float a = fr[j];
#pragma unroll
        for (int m = 0; m < 8; ++m) a = fmaf(fr[16 + m], kn[m * 17 + j], a);
        Ms[nx][i * 17 + j] = a;
      }
    } else if (tid >= 320 && tid < 336) {
      if (t + 1 < Tn) {
        const int i = tid - 320;
        const float* fr = &FsRing[((t + 1) & 3) * 384 + i * 24];
        const float* kn = &KkAll[(t + 1) * 136];
        float a = 0.f;
#pragma unroll
        for (int m = 0; m < 8; ++m) a = fmaf(fr[16 + m], kn[m * 17 + 16], a);
        bs[nx][i] = a;
      }
    } else if (tid >= 384) {
      const int j = tid - 384;
      if (t + 3 < Tn) {
        FsRing[((t + 3) & 3) * 384 + 2 * j]     = rfA0;
        FsRing[((t + 3) & 3) * 384 + 2 * j + 1] = rfA1;
      }
      rfA0 = rfB0; rfA1 = rfB1;
      if (t + 5 < Tn) {
        rfB0 = Fg[(size_t)((t + 5) * Bn + b) * 384 + 2 * j];
        rfB1 = Fg[(size_t)((t + 5) * Bn + b) * 384 + 2 * j + 1];
      }
    }
    __syncthreads();
  }

  // all du_t = K_t dx_t + k_t in parallel, write outputs
  if (tid < 512) {
    const int tt = tid >> 3, m = tid & 7;
    const float* kt2 = &KkAll[tt * 136 + m * 17];
    float a = kt2[16];
#pragma unroll
    for (int n = 0; n < 16; ++n) a = fmaf(kt2[n], dxAll[tt * 16 + n], a);
    const size_t o = (size_t)(tt * Bn + b) * 8 + m;
    outg[o] = unomg[o] + a;
  }
}

extern "C" void kernel_launch(void* const* d_in, const int* in_sizes, int n_in,
                              void* d_out, int out_size, void* d_ws, size_t ws_size,
                              hipStream_t stream) {
  (void)in_sizes; (void)n_in; (void)out_size; (void)d_ws; (void)ws_size;
  const float* Qg    = (const float*)d_in[0];
  const float* qg    = (const float*)d_in[1];
  const float* Fg    = (const float*)d_in[2];
  const float* Gg    = (const float*)d_in[3];
  const float* Wg    = (const float*)d_in[4];
  const float* cg    = (const float*)d_in[5];
  const float* sg    = (const float*)d_in[6];
  const float* VTg   = (const float*)d_in[7];
  const float* vTg   = (const float*)d_in[8];
  const float* x0g   = (const float*)d_in[9];
  const float* xnomg = (const float*)d_in[10];
  const float* unomg = (const float*)d_in[11];
  float* outg = (float*)d_out;

  ipddp_kernel<<<dim3(Bn), dim3(576), 0, stream>>>(
      Qg, qg, Fg, Gg, Wg, cg, sg, VTg, vTg, x0g, xnomg, unomg, outg);
}

// Round 3
// 259.821 us; speedup vs baseline: 1.5406x; 1.1162x over previous
//
#include <hip/hip_runtime.h>
#include <math.h>

#define Tn 64
#define Bn 128
#define MUc 0.1f
#define REGc 1e-6f

// ---- dynamic LDS layout (float offsets) ----
#define OG    0        // Gbuf[2][9216]
#define OQb   18432    // Qbuf[2][576]
#define OFb   19584    // Fbuf[2][384]
#define OWb   20352    // Wbuf[2][192]
#define Oqv   20736    // qbuf[2][24]
#define Ocv   20784    // cbuf[2][8]
#define Osv   20800    // sbuf[2][8]
#define OFtV  20816    // FtV[24*16]
#define OWT   21200    // WT[24*12]
#define OWTs  21488    // WTs[24*12]
#define OQh   21776    // Qh[576]
#define OAs   22352    // As[16*17]
#define OAsT  22624    // AsT[16*17]
#define Ovls  22896    // v carry[16]
#define Oqh2  22912    // qh[24]
#define Oscl  22936    // scls[8]
#define Ow2   22944    // w2ls[8]
#define OK    22960    // KkAll[64*136]
#define OMs   31664    // fwd M[2][272]
#define Obs   32208    // fwd b[2][16]
#define Odx   32240    // dx[65*16]
#define OFr   33280    // fwd F ring[4*384]
#define SMEMF 34816    // total floats (139264 B)

#define AS1C(p) ((const __attribute__((address_space(1))) void*)(p))
#define AS3(p)  ((__attribute__((address_space(3))) void*)(p))
#define GLD16(gp, lp) __builtin_amdgcn_global_load_lds(AS1C(gp), AS3(lp), 16, 0, 0)
#define GLD4(gp, lp)  __builtin_amdgcn_global_load_lds(AS1C(gp), AS3(lp), 4, 0, 0)

__global__ __launch_bounds__(576, 1) void ipddp_kernel(
    const float* __restrict__ Qg, const float* __restrict__ qg,
    const float* __restrict__ Fg, const float* __restrict__ Gg,
    const float* __restrict__ Wg, const float* __restrict__ cg,
    const float* __restrict__ sg, const float* __restrict__ VTg,
    const float* __restrict__ vTg, const float* __restrict__ x0g,
    const float* __restrict__ xnomg, const float* __restrict__ unomg,
    float* __restrict__ outg)
{
  extern __shared__ float sm[];
  const int b   = blockIdx.x;
  const int tid = threadIdx.x;
  const int wv  = tid >> 6;        // wave 0..8
  const int ln  = tid & 63;
  const int qi  = tid / 24;
  const int qj  = tid - qi * 24;

  // async-stage one timestep's inputs into buffer nx (no VGPRs held)
  auto STAGE = [&](size_t pb, int nx) {
    const float* gsrc = Gg + pb * 9216;
    float* gdst = sm + OG + nx * 9216;
#pragma unroll
    for (int r = 0; r < 4; ++r) {
      const int ci = wv * 4 + r;                 // 36 chunks of 1024B
      GLD16(gsrc + ci * 256 + ln * 4, gdst + ci * 256);
    }
    GLD4(Qg + pb * 576 + wv * 64 + ln, sm + OQb + nx * 576 + wv * 64);
    if (wv < 6) GLD4(Fg + pb * 384 + wv * 64 + ln, sm + OFb + nx * 384 + wv * 64);
    else        GLD4(Wg + pb * 192 + (wv - 6) * 64 + ln, sm + OWb + nx * 192 + (wv - 6) * 64);
    if (wv == 0 && ln < 24) GLD4(qg + pb * 24 + ln, sm + Oqv + nx * 24);
    if (wv == 1 && ln < 8)  GLD4(cg + pb * 8 + ln,  sm + Ocv + nx * 8);
    if (wv == 2 && ln < 8)  GLD4(sg + pb * 8 + ln,  sm + Osv + nx * 8);
  };

  // ---------------- prologue: stage t=63 into buf1, init carries ----------------
  {
    const size_t pb = (size_t)((Tn - 1) * Bn + b);
    STAGE(pb, 1);
    if (tid < 256) {
      const float v = VTg[(size_t)b * 256 + tid];
      const int n = tid >> 4, m = tid & 15;
      sm[OAs + n * 17 + m] = v;
      sm[OAsT + m * 17 + n] = v;
    }
    if (tid < 16) sm[Ovls + tid] = vTg[(size_t)b * 16 + tid];
    if (tid >= 512 && tid < 520) {
      const int c2 = tid - 512;
      const float cc = cg[pb * 8 + c2], ss = sg[pb * 8 + c2];
      const float rr = fmaf(ss, cc, MUc);
      sm[Oscl + c2] = ss / cc;
      sm[Ow2 + c2]  = ss - rr / cc;
    }
    asm volatile("s_waitcnt vmcnt(0)" ::: "memory");
    __syncthreads();
  }

  // ---------------- backward scan ----------------
  for (int t = Tn - 1; t >= 0; --t) {
    const int p = t & 1, nx = p ^ 1;
    const int tp = (t > 0) ? (t - 1) : 0;
    const float* Gb = sm + OG  + p * 9216;
    const float* Qb = sm + OQb + p * 576;
    const float* Fb = sm + OFb + p * 384;
    const float* Wb = sm + OWb + p * 192;

    // P1: issue async staging for t-1; compute FtV = F^T V, WT/WTs, qh
    STAGE((size_t)(tp * Bn + b), nx);
    if (tid < 384) {
      const int i = tid >> 4, m = tid & 15;
      float a = 0.f;
#pragma unroll
      for (int n = 0; n < 16; ++n)
        a = fmaf(Fb[n * 24 + i], sm[OAs + n * 17 + m] + sm[OAsT + n * 17 + m], a);
      sm[OFtV + i * 16 + m] = 0.5f * a;
    } else {
      const int idx = tid - 384, d = idx >> 3, c = idx & 7;
      const float w = Wb[c * 24 + d];
      sm[OWT + d * 12 + c]  = w;
      sm[OWTs + d * 12 + c] = w * sm[Oscl + c];
      if (tid >= 552) {
        const int i = tid - 552;
        float a = sm[Oqv + p * 24 + i];
#pragma unroll
        for (int n = 0; n < 16; ++n) a = fmaf(Fb[n * 24 + i], sm[Ovls + n], a);
#pragma unroll
        for (int c2 = 0; c2 < 8; ++c2) a = fmaf(Wb[c2 * 24 + i], sm[Ow2 + c2], a);
        sm[Oqh2 + i] = a;
      }
    }
    __syncthreads();

    // P2: Qh[i][j]
    {
      float acc = Qb[tid];
      const float4* fa = (const float4*)(sm + OFtV + qi * 16);
#pragma unroll
      for (int r = 0; r < 4; ++r) {
        const float4 x4 = fa[r];
        acc = fmaf(x4.x, Fb[(4 * r + 0) * 24 + qj], acc);
        acc = fmaf(x4.y, Fb[(4 * r + 1) * 24 + qj], acc);
        acc = fmaf(x4.z, Fb[(4 * r + 2) * 24 + qj], acc);
        acc = fmaf(x4.w, Fb[(4 * r + 3) * 24 + qj], acc);
      }
#pragma unroll
      for (int n = 0; n < 16; ++n) acc = fmaf(sm[Ovls + n], Gb[n * 576 + tid], acc);
      const float4* wa = (const float4*)(sm + OWT + qi * 12);
      const float4* wb = (const float4*)(sm + OWTs + qj * 12);
#pragma unroll
      for (int r = 0; r < 2; ++r) {
        const float4 x4 = wa[r], y4 = wb[r];
        acc = fmaf(x4.x, -y4.x, acc); acc = fmaf(x4.y, -y4.y, acc);
        acc = fmaf(x4.z, -y4.z, acc); acc = fmaf(x4.w, -y4.w, acc);
      }
      sm[OQh + tid] = acc;
    }
    __syncthreads();

    // P3: wave 0 — no-pivot LU (Quu strongly PD), 17 RHS column-per-lane;
    //     Schur form: no Z/z needed. Also v_new on lanes 0..15.
    if (tid < 64) {
      float colv[8], invk[8];
#pragma unroll
      for (int a = 0; a < 8; ++a) colv[a] = 0.f;
      if (ln < 8) {
#pragma unroll
        for (int a = 0; a < 8; ++a) colv[a] = sm[OQh + (16 + a) * 24 + 16 + ln];
        colv[ln] += REGc;
      } else if (ln < 24) {
#pragma unroll
        for (int a = 0; a < 8; ++a) colv[a] = sm[OQh + (16 + a) * 24 + (ln - 8)];
      } else if (ln == 24) {
#pragma unroll
        for (int a = 0; a < 8; ++a) colv[a] = sm[Oqh2 + 16 + a];
      }
#pragma unroll
      for (int k = 0; k < 8; ++k) {
        const float ckk = __shfl(colv[k], k);
        const float inv = 1.0f / ckk;
        invk[k] = inv;
#pragma unroll
        for (int a = k + 1; a < 8; ++a) {
          const float m = __shfl(colv[a], k) * inv;
          colv[a] = fmaf(-m, colv[k], colv[a]);
        }
      }
      float x[8];
#pragma unroll
      for (int a = 7; a >= 0; --a) {
        float acc = colv[a];
#pragma unroll
        for (int j2 = a + 1; j2 < 8; ++j2) acc = fmaf(-__shfl(colv[a], j2), x[j2], acc);
        x[a] = acc * invk[a];
      }
      if (ln >= 8 && ln <= 24) {
        const int cc = ln - 8;
#pragma unroll
        for (int a = 0; a < 8; ++a) sm[OK + t * 136 + a * 17 + cc] = -x[a];
      }
      float kt[8];
#pragma unroll
      for (int a = 0; a < 8; ++a) kt[a] = -__shfl(x[a], 24);
      if (ln < 16) {
        float a = sm[Oqh2 + ln];
#pragma unroll
        for (int m2 = 0; m2 < 8; ++m2) a = fmaf(sm[OQh + ln * 24 + 16 + m2], kt[m2], a);
        sm[Ovls + ln] = a;
      }
    }
    __syncthreads();

    // P4: A = Qxx + Qxu*K (Schur V), dual-write for symmetrization;
    //     scls/w2ls for t-1 after vmcnt drain; drain all staging.
    if (tid < 256) {
      const int n = tid >> 4, m = tid & 15;
      const float* kk = sm + OK + t * 136;
      float a = sm[OQh + n * 24 + m];
#pragma unroll
      for (int k2 = 0; k2 < 8; ++k2) a = fmaf(sm[OQh + n * 24 + 16 + k2], kk[k2 * 17 + m], a);
      sm[OAs + n * 17 + m] = a;
      sm[OAsT + m * 17 + n] = a;
    } else if (tid >= 512 && tid < 520) {
      const int c2 = tid - 512;
      asm volatile("s_waitcnt vmcnt(0)" ::: "memory");
      const float cc = sm[Ocv + nx * 8 + c2], ss = sm[Osv + nx * 8 + c2];
      const float rr = fmaf(ss, cc, MUc);
      sm[Oscl + c2] = ss / cc;
      sm[Ow2 + c2]  = ss - rr / cc;
    }
    asm volatile("s_waitcnt vmcnt(0)" ::: "memory");
    __syncthreads();
  }

  // ---------------- forward rollout ----------------
  float rfA0 = 0.f, rfA1 = 0.f, rfB0 = 0.f, rfB1 = 0.f;
  if (tid >= 384) {
    const int j = tid - 384;
#pragma unroll
    for (int slot = 0; slot < 3; ++slot) {
      sm[OFr + slot * 384 + 2 * j]     = Fg[(size_t)(slot * Bn + b) * 384 + 2 * j];
      sm[OFr + slot * 384 + 2 * j + 1] = Fg[(size_t)(slot * Bn + b) * 384 + 2 * j + 1];
    }
    rfA0 = Fg[(size_t)(3 * Bn + b) * 384 + 2 * j];
    rfA1 = Fg[(size_t)(3 * Bn + b) * 384 + 2 * j + 1];
    rfB0 = Fg[(size_t)(4 * Bn + b) * 384 + 2 * j];
    rfB1 = Fg[(size_t)(4 * Bn + b) * 384 + 2 * j + 1];
  }
  if (tid < 16) sm[Odx + tid] = x0g[(size_t)b * 16 + tid] - xnomg[(size_t)b * 16 + tid];
  __syncthreads();

  // M0 = fx0 + fu0*K0, b0 = fu0*k0
  if (tid >= 64 && tid < 320) {
    const int idx = tid - 64, i = idx >> 4, j = idx & 15;
    const float* fr = sm + OFr + i * 24;
    float a = fr[j];
#pragma unroll
    for (int m = 0; m < 8; ++m) a = fmaf(fr[16 + m], sm[OK + m * 17 + j], a);
    sm[OMs + i * 17 + j] = a;
  } else if (tid >= 320 && tid < 336) {
    const int i = tid - 320;
    const float* fr = sm + OFr + i * 24;
    float a = 0.f;
#pragma unroll
    for (int m = 0; m < 8; ++m) a = fmaf(fr[16 + m], sm[OK + m * 17 + 16], a);
    sm[Obs + i] = a;
  }
  __syncthreads();

  for (int t = 0; t < Tn; ++t) {
    const int cur = t & 1, nx2 = (t + 1) & 1;
    if (tid < 16) {
      const int i = tid;
      float a = sm[Obs + cur * 16 + i];
#pragma unroll
      for (int k2 = 0; k2 < 16; ++k2)
        a = fmaf(sm[OMs + cur * 272 + i * 17 + k2], sm[Odx + t * 16 + k2], a);
      sm[Odx + (t + 1) * 16 + i] = a;
    } else if (tid >= 64 && tid < 320) {
      if (t + 1 < Tn) {
        const int idx = tid - 64, i = idx >> 4, j = idx & 15;
        const float* fr = sm + OFr + ((t + 1) & 3) * 384 + i * 24;
        const float* kn = sm + OK + (t + 1) * 136;
        float a = fr[j];
#pragma unroll
        for (int m = 0; m < 8; ++m) a = fmaf(fr[16 + m], kn[m * 17 + j], a);
        sm[OMs + nx2 * 272 + i * 17 + j] = a;
      }
    } else if (tid >= 320 && tid < 336) {
      if (t + 1 < Tn) {
        const int i = tid - 320;
        const float* fr = sm + OFr + ((t + 1) & 3) * 384 + i * 24;
        const float* kn = sm + OK + (t + 1) * 136;
        float a = 0.f;
#pragma unroll
        for (int m = 0; m < 8; ++m) a = fmaf(fr[16 + m], kn[m * 17 + 16], a);
        sm[Obs + nx2 * 16 + i] = a;
      }
    } else if (tid >= 384) {
      const int j = tid - 384;
      if (t + 3 < Tn) {
        sm[OFr + ((t + 3) & 3) * 384 + 2 * j]     = rfA0;
        sm[OFr + ((t + 3) & 3) * 384 + 2 * j + 1] = rfA1;
      }
      rfA0 = rfB0; rfA1 = rfB1;
      if (t + 5 < Tn) {
        rfB0 = Fg[(size_t)((t + 5) * Bn + b) * 384 + 2 * j];
        rfB1 = Fg[(size_t)((t + 5) * Bn + b) * 384 + 2 * j + 1];
      }
    }
    __syncthreads();
  }

  // all du_t = K_t dx_t + k_t in parallel, write outputs
  if (tid < 512) {
    const int tt = tid >> 3, m = tid & 7;
    const float* kt2 = sm + OK + tt * 136 + m * 17;
    float a = kt2[16];
#pragma unroll
    for (int n = 0; n < 16; ++n) a = fmaf(kt2[n], sm[Odx + tt * 16 + n], a);
    const size_t o = (size_t)(tt * Bn + b) * 8 + m;
    outg[o] = unomg[o] + a;
  }
}

extern "C" void kernel_launch(void* const* d_in, const int* in_sizes, int n_in,
                              void* d_out, int out_size, void* d_ws, size_t ws_size,
                              hipStream_t stream) {
  (void)in_sizes; (void)n_in; (void)out_size; (void)d_ws; (void)ws_size;
  const float* Qg    = (const float*)d_in[0];
  const float* qg    = (const float*)d_in[1];
  const float* Fg    = (const float*)d_in[2];
  const float* Gg    = (const float*)d_in[3];
  const float* Wg    = (const float*)d_in[4];
  const float* cg    = (const float*)d_in[5];
  const float* sg    = (const float*)d_in[6];
  const float* VTg   = (const float*)d_in[7];
  const float* vTg   = (const float*)d_in[8];
  const float* x0g   = (const float*)d_in[9];
  const float* xnomg = (const float*)d_in[10];
  const float* unomg = (const float*)d_in[11];
  float* outg = (float*)d_out;

  (void)hipFuncSetAttribute((const void*)ipddp_kernel,
                            hipFuncAttributeMaxDynamicSharedMemorySize,
                            SMEMF * 4);
  ipddp_kernel<<<dim3(Bn), dim3(576), SMEMF * 4, stream>>>(
      Qg, qg, Fg, Gg, Wg, cg, sg, VTg, vTg, x0g, xnomg, unomg, outg);
}